// Round 9
// baseline (94.976 us; speedup 1.0000x reference)
//
#include <hip/hip_runtime.h>
#include <hip/hip_bf16.h>

#define D 32
#define FACTOR (-1.0f / 128.0f)   // -1/(2*8^2)
#define LOG2E  1.44269504088896340736f

typedef __attribute__((ext_vector_type(8)))  short bf16x8;
typedef __attribute__((ext_vector_type(16))) float f32x16;
typedef __attribute__((ext_vector_type(4)))  float f32x4;

#if __has_builtin(__builtin_amdgcn_exp2f)
#define EXP2(x) __builtin_amdgcn_exp2f(x)
#else
#define EXP2(x) exp2f(x)
#endif

__device__ __forceinline__ ushort bfr(float x) {
    __hip_bfloat16 h = __float2bfloat16(x);     // RNE
    return *reinterpret_cast<ushort*>(&h);
}
__device__ __forceinline__ float bf2f(ushort u) {
    uint w = ((uint)u) << 16;
    return *reinterpret_cast<float*>(&w);
}
__device__ __forceinline__ uint pk2(float a, float b) {
    return (uint)bfr(a) | ((uint)bfr(b) << 16);
}

union U4 { uint4 q; bf16x8 v; uint u[4]; };

// ---------------------------------------------------------------------------
// Prep: bf16 copies of X and Y, B-fragment-ordered tiled transpose
// yT[m/32][d][slot] (slot = ks*16 + h*8 + j so a B-frag is one dwordx4),
// and y2s[m] = (FACTOR*LOG2E)*||y~_m||^2 (x^2 term cancels in nom/den).
// ---------------------------------------------------------------------------
__global__ __launch_bounds__(256) void msk_prep(const float* __restrict__ X,
                                                const float* __restrict__ Y,
                                                ushort* __restrict__ Xb,
                                                ushort* __restrict__ Yb,
                                                ushort* __restrict__ yT,
                                                float* __restrict__ y2s,
                                                int N, int M) {
    const int t = blockIdx.x * 256 + threadIdx.x;
    const int i = t >> 2;
    const int c = t & 3;
    if (i >= N + M) return;
    const bool isX = (i < N);
    const int r = isX ? i : i - N;
    const float* src = (isX ? X : Y) + (size_t)r * D + c * 8;

    float4 va = *reinterpret_cast<const float4*>(src);
    float4 vb = *reinterpret_cast<const float4*>(src + 4);
    float f[8] = {va.x, va.y, va.z, va.w, vb.x, vb.y, vb.z, vb.w};

    ushort u[8];
    float s = 0.f;
#pragma unroll
    for (int k = 0; k < 8; ++k) {
        u[k] = bfr(f[k]);
        float g = bf2f(u[k]);
        s = fmaf(g, g, s);
    }
    s += __shfl_xor(s, 1);
    s += __shfl_xor(s, 2);

    uint w[4];
#pragma unroll
    for (int q = 0; q < 4; ++q) w[q] = (uint)u[2 * q] | ((uint)u[2 * q + 1] << 16);

    ushort* dstrow = (isX ? Xb : Yb) + (size_t)r * D + c * 8;
    *reinterpret_cast<uint4*>(dstrow) = *reinterpret_cast<const uint4*>(w);

    if (!isX) {
        if (c == 0) y2s[r] = s * (FACTOR * LOG2E);
        // slot(m): m = 16ks + 8b + 4h + a  ->  slot = 16ks + 8h + 4b + a
        const int ml   = r & 31;
        const int slot = ((ml >> 4) << 4) | (((ml >> 2) & 1) << 3)
                       | (((ml >> 3) & 1) << 2) | (ml & 3);
        ushort* yt = yT + (size_t)(r >> 5) * 1024 + slot;
#pragma unroll
        for (int k = 0; k < 8; ++k)
            yt[(c * 8 + k) * 32] = u[k];
    }
}

// ---------------------------------------------------------------------------
// Main fused kernel — NO LDS, NO barriers. All operands are L2-resident
// (~3 MB working set); every load is a coalesced dwordx4. Each wave owns a
// 32-n tile and streams its m-chunk in 32-m tiles with 2-deep register
// prefetch (named A/B sets, static indexing). Per tile:
//   GEMM1: S^T = y_tile . x^T  (2x mfma_32x32x16_bf16, K=32)
//   k' = exp2(dot*C2 + y2s[m]); pack to bf16 (per-lane m-order absorbed
//   into yT's slot layout); GEMM2: nom += K'.Y (2x mfma).
// ---------------------------------------------------------------------------
__global__ __launch_bounds__(256, 4) void msk_main(const ushort* __restrict__ Xb,
                                                   const ushort* __restrict__ Yb,
                                                   const ushort* __restrict__ yT,
                                                   const float* __restrict__ y2s,
                                                   float* __restrict__ pnom,
                                                   float* __restrict__ pden,
                                                   int N, int M, int chunk) {
    const int lane = threadIdx.x & 63;
    const int wid  = threadIdx.x >> 6;
    const int h    = lane >> 5;
    const int ln   = lane & 31;
    const int n0   = blockIdx.x * 128 + wid * 32;
    const int m0b  = blockIdx.y * chunk;
    const int nt   = chunk >> 5;                 // 32-m tiles per wave

    // x B-fragments: element (h,j) <-> d = 16*ks + 8h + j
    const ushort* xrow = Xb + (size_t)(n0 + ln) * D + h * 8;
    const bf16x8 xf0 = *reinterpret_cast<const bf16x8*>(xrow);
    const bf16x8 xf1 = *reinterpret_cast<const bf16x8*>(xrow + 16);

    const float C2 = -2.0f * (FACTOR * LOG2E);

    f32x16 nom = {};
    float den0 = 0.f, den1 = 0.f;

    U4 Ay0, Ay1, At0, At1, By0, By1, Bt0, Bt1;

#define LOADT(M0, Y0, Y1, T0, T1)                                              \
    {                                                                          \
        const ushort* yb_ = Yb + (size_t)((M0) + ln) * D + h * 8;              \
        Y0.q = *reinterpret_cast<const uint4*>(yb_);                           \
        Y1.q = *reinterpret_cast<const uint4*>(yb_ + 16);                      \
        const ushort* yt_ = yT + (size_t)((M0) >> 5) * 1024 + ln * 32 + h * 8; \
        T0.q = *reinterpret_cast<const uint4*>(yt_);                           \
        T1.q = *reinterpret_cast<const uint4*>(yt_ + 16);                      \
    }

#define COMPT(MT, Y0, Y1, T0, T1)                                              \
    {                                                                          \
        f32x16 s = {};                                                         \
        s = __builtin_amdgcn_mfma_f32_32x32x16_bf16(Y0.v, xf0, s, 0, 0, 0);    \
        s = __builtin_amdgcn_mfma_f32_32x32x16_bf16(Y1.v, xf1, s, 0, 0, 0);    \
        U4 pa0, pa1;                                                           \
        _Pragma("unroll")                                                      \
        for (int r4 = 0; r4 < 4; ++r4) {                                       \
            f32x4 yv = *reinterpret_cast<const f32x4*>(y2s + (MT) + r4 * 8 + h * 4); \
            float k0 = EXP2(fmaf(s[r4 * 4 + 0], C2, yv[0]));                   \
            float k1 = EXP2(fmaf(s[r4 * 4 + 1], C2, yv[1]));                   \
            float k2 = EXP2(fmaf(s[r4 * 4 + 2], C2, yv[2]));                   \
            float k3 = EXP2(fmaf(s[r4 * 4 + 3], C2, yv[3]));                   \
            den0 += k0 + k1;                                                   \
            den1 += k2 + k3;                                                   \
            uint w0 = pk2(k0, k1);                                             \
            uint w1 = pk2(k2, k3);                                             \
            if (r4 < 2) { pa0.u[r4 * 2] = w0; pa0.u[r4 * 2 + 1] = w1; }        \
            else        { pa1.u[(r4 - 2) * 2] = w0; pa1.u[(r4 - 2) * 2 + 1] = w1; } \
        }                                                                      \
        nom = __builtin_amdgcn_mfma_f32_32x32x16_bf16(pa0.v, T0.v, nom, 0, 0, 0); \
        nom = __builtin_amdgcn_mfma_f32_32x32x16_bf16(pa1.v, T1.v, nom, 0, 0, 0); \
    }

    LOADT(m0b, Ay0, Ay1, At0, At1);
    if (nt > 1) LOADT(m0b + 32, By0, By1, Bt0, Bt1);

    for (int it = 0; it < nt; it += 2) {
        const int mA = m0b + it * 32;
        COMPT(mA, Ay0, Ay1, At0, At1);
        if (it + 2 < nt) LOADT(mA + 64, Ay0, Ay1, At0, At1);
        if (it + 1 < nt) COMPT(mA + 32, By0, By1, Bt0, Bt1);
        if (it + 3 < nt) LOADT(mA + 96, By0, By1, Bt0, Bt1);
    }
#undef LOADT
#undef COMPT

    // den: halves hold disjoint m partials for the same n=ln
    float den = den0 + den1;
    den += __shfl_xor(den, 32);

    const size_t base = (size_t)blockIdx.y * N;
#pragma unroll
    for (int r = 0; r < 16; ++r) {
        const int row = (r & 3) + 8 * (r >> 2) + 4 * h;      // n offset
        pnom[(base + n0 + row) * 32 + ln] = nom[r];          // d = ln
    }
    if (h == 0) pden[base + n0 + ln] = den;
}

// ---------------------------------------------------------------------------
// Reduce over m-chunks and divide.
// ---------------------------------------------------------------------------
__global__ __launch_bounds__(256) void msk_reduce(const float* __restrict__ pnom,
                                                  const float* __restrict__ pden,
                                                  float* __restrict__ out,
                                                  int N, int S) {
    const int t = blockIdx.x * blockDim.x + threadIdx.x;
    if (t >= N * 32) return;
    const int n = t >> 5;
    float nom = 0.f, den = 0.f;
    for (int s = 0; s < S; ++s) {
        nom += pnom[(size_t)s * N * 32 + t];
        den += pden[(size_t)s * N + n];
    }
    out[t] = nom / den;
}

// ---------------------------------------------------------------------------
extern "C" void kernel_launch(void* const* d_in, const int* in_sizes, int n_in,
                              void* d_out, int out_size, void* d_ws, size_t ws_size,
                              hipStream_t stream) {
    const float* X = (const float*)d_in[0];
    const float* Y = (const float*)d_in[1];
    float* out     = (float*)d_out;

    const int N = in_sizes[0] / D;   // 8192
    const int M = in_sizes[1] / D;   // 8192

    char* p = (char*)d_ws;
    ushort* Xb  = (ushort*)p; p += (size_t)N * D * sizeof(ushort);
    ushort* Yb  = (ushort*)p; p += (size_t)M * D * sizeof(ushort);
    ushort* yT  = (ushort*)p; p += (size_t)M * D * sizeof(ushort);   // tiled [M/32][32][32]
    float*  y2s = (float*)p;  p += (size_t)M * sizeof(float);
    size_t used = (size_t)(p - (char*)d_ws);
    used = (used + 255) & ~(size_t)255;

    const size_t per_s = (size_t)N * 33 * sizeof(float);
    int S = 16;                                  // 1024 blocks = 4/CU
    while (S > 1 && used + (size_t)S * per_s > ws_size) S >>= 1;
    const int chunk = M / S;                     // 512 -> 16 tiles of 32 m

    float* pnom = (float*)((char*)d_ws + used);
    float* pden = pnom + (size_t)S * N * 32;

    msk_prep<<<dim3(((N + M) * 4 + 255) / 256), dim3(256), 0, stream>>>(
        X, Y, Xb, Yb, yT, y2s, N, M);

    msk_main<<<dim3(N / 128, S), dim3(256), 0, stream>>>(
        Xb, Yb, yT, y2s, pnom, pden, N, M, chunk);

    msk_reduce<<<dim3((N * 32 + 255) / 256), dim3(256), 0, stream>>>(
        pnom, pden, out, N, S);
}